// Round 3
// baseline (280.717 us; speedup 1.0000x reference)
//
#include <hip/hip_runtime.h>

constexpr float ALPHA = 0.001f;
constexpr float BETA  = 0.001f;
constexpr int R   = 64;
constexpr int S   = 3;
constexpr int PFW = R * (1 + 2 * S); // 448 floats per pF row
constexpr int BUCKET_SHIFT = 7;      // 128 pF rows/bucket = 229 KB L2 region
constexpr int NBLK = 128;            // chunks for the counting sort
constexpr int MAXB = 800;            // LDS histogram capacity (>= 782 buckets)

// ---- A: per-block histogram (LDS atomics only), transposed store ----
__global__ __launch_bounds__(256) void blockhist_kernel(
    const int* __restrict__ ijk, int B, int chunk, int nb, int* __restrict__ ghist)
{
    __shared__ int lh[MAXB];
    for (int t = threadIdx.x; t < nb; t += blockDim.x) lh[t] = 0;
    __syncthreads();
    const int lo = blockIdx.x * chunk;
    const int hi = min(B, lo + chunk);
    for (int idx = lo + threadIdx.x; idx < hi; idx += blockDim.x)
        atomicAdd(&lh[ijk[3 * idx] >> BUCKET_SHIFT], 1);
    __syncthreads();
    for (int t = threadIdx.x; t < nb; t += blockDim.x)
        ghist[t * NBLK + blockIdx.x] = lh[t];   // bucket-major
}

// ---- B: in-place exclusive scan over n = nb*NBLK elements ----
__global__ __launch_bounds__(1024) void scan_kernel(int* __restrict__ g, int n)
{
    __shared__ int tot[1024];
    const int t = threadIdx.x;
    const int seg = (n + 1023) / 1024;
    const int lo = t * seg, hi = min(n, lo + seg);
    int s = 0;
    for (int e = lo; e < hi; ++e) s += g[e];
    tot[t] = s;
    __syncthreads();
    for (int d = 1; d < 1024; d <<= 1) {
        int v = (t >= d) ? tot[t - d] : 0;
        __syncthreads();
        tot[t] += v;
        __syncthreads();
    }
    int run = (t == 0) ? 0 : tot[t - 1];
    for (int e = lo; e < hi; ++e) { int v = g[e]; g[e] = run; run += v; }
}

// ---- C: scatter into sorted int4{i,j,k,b} using LDS counters (no global atomics) ----
__global__ __launch_bounds__(256) void scatter_kernel(
    const int* __restrict__ ijk, int B, int chunk, int nb,
    const int* __restrict__ offs, int4* __restrict__ sorted)
{
    __shared__ int lcnt[MAXB];
    for (int t = threadIdx.x; t < nb; t += blockDim.x)
        lcnt[t] = offs[t * NBLK + blockIdx.x];
    __syncthreads();
    const int lo = blockIdx.x * chunk;
    const int hi = min(B, lo + chunk);
    for (int idx = lo + threadIdx.x; idx < hi; idx += blockDim.x) {
        const int i = ijk[3 * idx], j = ijk[3 * idx + 1], k = ijk[3 * idx + 2];
        const int p = atomicAdd(&lcnt[i >> BUCKET_SHIFT], 1);
        sorted[p] = make_int4(i, j, k, idx);
    }
}

// ---- main: 16 lanes per b, 2 b's per group, bucket-ordered, XCD-chunked ----
__global__ __launch_bounds__(256) void mf_if_kernel(
    const float* __restrict__ pF,
    const float* __restrict__ M,
    const int4*  __restrict__ sorted,  // may be null -> identity order via ijk
    const int*   __restrict__ ijk,
    float* __restrict__ out,
    int B, int nwg)
{
    // bijective XCD-chunked swizzle (m204)
    const int orig = blockIdx.x;
    const int q = nwg >> 3, r = nwg & 7;
    const int xcd = orig & 7;
    const int wgid = (xcd < r ? xcd * (q + 1) : r * (q + 1) + (xcd - r) * q) + (orig >> 3);

    const int lane = threadIdx.x & 63;
    const int sub  = lane & 15;
    const int g    = threadIdx.x >> 4;          // 16 groups per block
    const long pos0 = (long)wgid * 32 + 2 * g;  // 32 b's per block
    if (pos0 >= B) return;
    const long pos1 = (pos0 + 1 < B) ? pos0 + 1 : pos0;
    const bool do1  = (pos0 + 1 < B);

    int4 s0, s1;
    if (sorted) {
        s0 = sorted[pos0];
        s1 = sorted[pos1];
    } else {
        s0 = make_int4(ijk[3 * pos0], ijk[3 * pos0 + 1], ijk[3 * pos0 + 2], (int)pos0);
        s1 = make_int4(ijk[3 * pos1], ijk[3 * pos1 + 1], ijk[3 * pos1 + 2], (int)pos1);
    }

    const int kc0 = (s0.z < 0) ? 0 : s0.z;
    const int kc1 = (s1.z < 0) ? 0 : s1.z;

    const float4* pFi0 = reinterpret_cast<const float4*>(pF + (size_t)s0.x * PFW);
    const float4* pFi1 = reinterpret_cast<const float4*>(pF + (size_t)s1.x * PFW);

    // issue all loads up front (MLP)
    const float4 mj0 = reinterpret_cast<const float4*>(M + (size_t)s0.y * R)[sub];
    const float4 mk0 = reinterpret_cast<const float4*>(M + (size_t)kc0 * R)[sub];
    const float4 pi0 = pFi0[sub];
    const float4 v00 = pFi0[16 + 3 * sub + 0];
    const float4 v01 = pFi0[16 + 3 * sub + 1];
    const float4 v02 = pFi0[16 + 3 * sub + 2];
    const float4 w00 = pFi0[64 + 3 * sub + 0];
    const float4 w01 = pFi0[64 + 3 * sub + 1];
    const float4 w02 = pFi0[64 + 3 * sub + 2];

    const float4 mj1 = reinterpret_cast<const float4*>(M + (size_t)s1.y * R)[sub];
    const float4 mk1 = reinterpret_cast<const float4*>(M + (size_t)kc1 * R)[sub];
    const float4 pi1 = pFi1[sub];
    const float4 v10 = pFi1[16 + 3 * sub + 0];
    const float4 v11 = pFi1[16 + 3 * sub + 1];
    const float4 v12 = pFi1[16 + 3 * sub + 2];
    const float4 w10 = pFi1[64 + 3 * sub + 0];
    const float4 w11 = pFi1[64 + 3 * sub + 1];
    const float4 w12 = pFi1[64 + 3 * sub + 2];

    float p0 = pi0.x * mj0.x + pi0.y * mj0.y + pi0.z * mj0.z + pi0.w * mj0.w;
    float a00 = v00.x * mj0.x + v00.w * mj0.y + v01.z * mj0.z + v02.y * mj0.w;
    float a01 = v00.y * mj0.x + v01.x * mj0.y + v01.w * mj0.z + v02.z * mj0.w;
    float a02 = v00.z * mj0.x + v01.y * mj0.y + v02.x * mj0.z + v02.w * mj0.w;
    float g00 = w00.x * mk0.x + w00.w * mk0.y + w01.z * mk0.z + w02.y * mk0.w;
    float g01 = w00.y * mk0.x + w01.x * mk0.y + w01.w * mk0.z + w02.z * mk0.w;
    float g02 = w00.z * mk0.x + w01.y * mk0.y + w02.x * mk0.z + w02.w * mk0.w;

    float p1 = pi1.x * mj1.x + pi1.y * mj1.y + pi1.z * mj1.z + pi1.w * mj1.w;
    float a10 = v10.x * mj1.x + v10.w * mj1.y + v11.z * mj1.z + v12.y * mj1.w;
    float a11 = v10.y * mj1.x + v11.x * mj1.y + v11.w * mj1.z + v12.z * mj1.w;
    float a12 = v10.z * mj1.x + v11.y * mj1.y + v12.x * mj1.z + v12.w * mj1.w;
    float g10 = w10.x * mk1.x + w10.w * mk1.y + w11.z * mk1.z + w12.y * mk1.w;
    float g11 = w10.y * mk1.x + w11.x * mk1.y + w11.w * mk1.z + w12.z * mk1.w;
    float g12 = w10.z * mk1.x + w11.y * mk1.y + w12.x * mk1.z + w12.w * mk1.w;

    #pragma unroll
    for (int off = 8; off >= 1; off >>= 1) {
        p0  += __shfl_xor(p0,  off);
        a00 += __shfl_xor(a00, off);
        a01 += __shfl_xor(a01, off);
        a02 += __shfl_xor(a02, off);
        g00 += __shfl_xor(g00, off);
        g01 += __shfl_xor(g01, off);
        g02 += __shfl_xor(g02, off);
        p1  += __shfl_xor(p1,  off);
        a10 += __shfl_xor(a10, off);
        a11 += __shfl_xor(a11, off);
        a12 += __shfl_xor(a12, off);
        g10 += __shfl_xor(g10, off);
        g11 += __shfl_xor(g11, off);
        g12 += __shfl_xor(g12, off);
    }

    if (sub == 0) {
        const float mfm0 = (s0.z != -1)
            ? (BETA * BETA) * (a00 * g00 + a01 * g01 + a02 * g02) : 0.0f;
        out[s0.w] = ALPHA * p0 + mfm0;
        if (do1) {
            const float mfm1 = (s1.z != -1)
                ? (BETA * BETA) * (a10 * g10 + a11 * g11 + a12 * g12) : 0.0f;
            out[s1.w] = ALPHA * p1 + mfm1;
        }
    }
}

extern "C" void kernel_launch(void* const* d_in, const int* in_sizes, int n_in,
                              void* d_out, int out_size, void* d_ws, size_t ws_size,
                              hipStream_t stream) {
    const float* pF  = (const float*)d_in[0];
    const float* M   = (const float*)d_in[1];
    const int*   ijk = (const int*)d_in[2];
    float* out = (float*)d_out;

    const int B   = in_sizes[2] / 3;            // 500000
    const int N_P = in_sizes[0] / PFW;          // 100000
    const int nb  = (N_P + (1 << BUCKET_SHIFT) - 1) >> BUCKET_SHIFT; // 782

    // workspace: ghist/offs [nb*NBLK] ints (<=512KB slot) | sorted int4[B]
    const size_t sorted_off = 512 * 1024;
    const size_t need = sorted_off + (size_t)B * sizeof(int4);
    int4* sorted = nullptr;

    if (nb <= MAXB && ws_size >= need) {
        int* ghist = (int*)d_ws;
        sorted = (int4*)((char*)d_ws + sorted_off);
        const int chunk = (B + NBLK - 1) / NBLK;

        blockhist_kernel<<<NBLK, 256, 0, stream>>>(ijk, B, chunk, nb, ghist);
        scan_kernel<<<1, 1024, 0, stream>>>(ghist, nb * NBLK);
        scatter_kernel<<<NBLK, 256, 0, stream>>>(ijk, B, chunk, nb, ghist, sorted);
    }

    const int nwg = (B + 31) / 32;              // 32 b's per 256-thread block
    mf_if_kernel<<<nwg, 256, 0, stream>>>(pF, M, sorted, ijk, out, B, nwg);
}

// Round 5
// 97.948 us; speedup vs baseline: 2.8660x; 2.8660x over previous
//
#include <hip/hip_runtime.h>

constexpr float ALPHA = 0.001f;
constexpr float BETA  = 0.001f;
constexpr int R   = 64;
constexpr int S   = 3;
constexpr int PFW = R * (1 + 2 * S); // 448 floats per pF row
constexpr int BSH  = 7;              // 128 pF rows/bucket = 229 KB L2 region
constexpr int MAXB = 800;            // >= 782 buckets
constexpr int SBLK = 256;            // hist/scatter block count

__device__ __forceinline__ float bfhi(unsigned u) {
    union { unsigned u; float f; } c; c.u = u & 0xffff0000u; return c.f;
}
__device__ __forceinline__ float bflo(unsigned u) {
    union { unsigned u; float f; } c; c.u = u << 16; return c.f;
}

// ---- M fp32 -> bf16 (RNE), 8 floats per thread ----
__global__ __launch_bounds__(256) void convM_kernel(const float* __restrict__ M,
                                                    uint4* __restrict__ Mb, int n8) {
    int idx = blockIdx.x * 256 + threadIdx.x;
    if (idx >= n8) return;
    const float4* src = reinterpret_cast<const float4*>(M);
    float4 a = src[2 * idx], b = src[2 * idx + 1];
    union { float f; unsigned u; } c;
    unsigned w[8];
    c.f = a.x; w[0] = c.u; c.f = a.y; w[1] = c.u; c.f = a.z; w[2] = c.u; c.f = a.w; w[3] = c.u;
    c.f = b.x; w[4] = c.u; c.f = b.y; w[5] = c.u; c.f = b.z; w[6] = c.u; c.f = b.w; w[7] = c.u;
    #pragma unroll
    for (int t = 0; t < 8; ++t) w[t] = (w[t] + 0x7fffu + ((w[t] >> 16) & 1u)) >> 16;
    Mb[idx] = make_uint4(w[0] | (w[1] << 16), w[2] | (w[3] << 16),
                         w[4] | (w[5] << 16), w[6] | (w[7] << 16));
}

// ---- hist: LDS-aggregated, fire-and-forget global merge ----
__global__ __launch_bounds__(256) void hist_kernel(const int* __restrict__ ijk, int B,
                                                   int chunk, int nb, int* __restrict__ hist) {
    __shared__ int lh[MAXB];
    for (int t = threadIdx.x; t < nb; t += blockDim.x) lh[t] = 0;
    __syncthreads();
    const int lo = blockIdx.x * chunk, hi = min(B, lo + chunk);
    for (int idx = lo + threadIdx.x; idx < hi; idx += blockDim.x)
        atomicAdd(&lh[ijk[3 * idx] >> BSH], 1);
    __syncthreads();
    for (int t = threadIdx.x; t < nb; t += blockDim.x)
        if (lh[t]) atomicAdd(&hist[t], lh[t]);
}

// ---- scan 782 -> offs (exclusive) + cursor init ----
__global__ __launch_bounds__(1024) void scan_kernel(const int* __restrict__ hist,
                                                    int* __restrict__ offs,
                                                    int* __restrict__ cursor, int nb) {
    __shared__ int buf[1024];
    int t = threadIdx.x;
    int own = (t < nb) ? hist[t] : 0;
    buf[t] = own;
    __syncthreads();
    for (int d = 1; d < 1024; d <<= 1) {
        int v = (t >= d) ? buf[t - d] : 0;
        __syncthreads();
        buf[t] += v;
        __syncthreads();
    }
    if (t < nb) { int e = buf[t] - own; offs[t] = e; cursor[t] = e; }
}

// ---- scatter: two-pass, per-(block,bucket) range reservation ----
__global__ __launch_bounds__(256) void scatter_kernel(const int* __restrict__ ijk, int B,
                                                      int chunk, int nb,
                                                      int* __restrict__ cursor,
                                                      int4* __restrict__ sorted) {
    __shared__ int cnt[MAXB];
    __shared__ int base[MAXB];
    __shared__ int rnk[MAXB];
    for (int t = threadIdx.x; t < nb; t += blockDim.x) { cnt[t] = 0; rnk[t] = 0; }
    __syncthreads();
    const int lo = blockIdx.x * chunk, hi = min(B, lo + chunk);
    for (int idx = lo + threadIdx.x; idx < hi; idx += blockDim.x)
        atomicAdd(&cnt[ijk[3 * idx] >> BSH], 1);
    __syncthreads();
    for (int t = threadIdx.x; t < nb; t += blockDim.x)
        if (cnt[t]) base[t] = atomicAdd(&cursor[t], cnt[t]);
    __syncthreads();
    for (int idx = lo + threadIdx.x; idx < hi; idx += blockDim.x) {
        const int i = ijk[3 * idx], j = ijk[3 * idx + 1], k = ijk[3 * idx + 2];
        const int bkt = i >> BSH;
        const int p = base[bkt] + atomicAdd(&rnk[bkt], 1);
        sorted[p] = make_int4(i, j, k, idx);
    }
}

// ---- main: 16 lanes per b, 1 b per group, bucket-ordered, XCD-chunked ----
__global__ __launch_bounds__(256) void mf_if_kernel(
    const float* __restrict__ pF,
    const float* __restrict__ M,      // fp32 fallback
    const uint2* __restrict__ Mb,     // bf16 packed (16 uint2 per row), may be null
    const int4*  __restrict__ sorted, // may be null -> identity order via ijk
    const int*   __restrict__ ijk,
    float* __restrict__ out,
    int B, int nwg)
{
    // bijective XCD-chunked swizzle (m204)
    const int orig = blockIdx.x;
    const int q = nwg >> 3, r = nwg & 7;
    const int xcd = orig & 7;
    const int wgid = (xcd < r ? xcd * (q + 1) : r * (q + 1) + (xcd - r) * q) + (orig >> 3);

    const int sub = threadIdx.x & 15;
    const long pos = (long)wgid * 16 + (threadIdx.x >> 4);
    if (pos >= B) return;

    int4 s;
    if (sorted) s = sorted[pos];
    else s = make_int4(ijk[3 * pos], ijk[3 * pos + 1], ijk[3 * pos + 2], (int)pos);

    const int kc = (s.z < 0) ? 0 : s.z;

    const float4* pFi = reinterpret_cast<const float4*>(pF + (size_t)s.x * PFW);

    float4 mj, mk;
    if (Mb) {
        // row = 64 bf16 = 16 uint2; lane sub owns uint2 #sub (4 bf16)
        const uint2 uj = Mb[(size_t)s.y * 16 + sub];
        const uint2 uk = Mb[(size_t)kc  * 16 + sub];
        mj = make_float4(bflo(uj.x), bfhi(uj.x), bflo(uj.y), bfhi(uj.y));
        mk = make_float4(bflo(uk.x), bfhi(uk.x), bflo(uk.y), bfhi(uk.y));
    } else {
        mj = reinterpret_cast<const float4*>(M + (size_t)s.y * R)[sub];
        mk = reinterpret_cast<const float4*>(M + (size_t)kc  * R)[sub];
    }

    const float4 pi = pFi[sub];
    float p = pi.x * mj.x + pi.y * mj.y + pi.z * mj.z + pi.w * mj.w;

    const float4 v0 = pFi[16 + 3 * sub + 0];
    const float4 v1 = pFi[16 + 3 * sub + 1];
    const float4 v2 = pFi[16 + 3 * sub + 2];
    float a0 = v0.x * mj.x + v0.w * mj.y + v1.z * mj.z + v2.y * mj.w;
    float a1 = v0.y * mj.x + v1.x * mj.y + v1.w * mj.z + v2.z * mj.w;
    float a2 = v0.z * mj.x + v1.y * mj.y + v2.x * mj.z + v2.w * mj.w;

    const float4 w0 = pFi[64 + 3 * sub + 0];
    const float4 w1 = pFi[64 + 3 * sub + 1];
    const float4 w2 = pFi[64 + 3 * sub + 2];
    float g0 = w0.x * mk.x + w0.w * mk.y + w1.z * mk.z + w2.y * mk.w;
    float g1 = w0.y * mk.x + w1.x * mk.y + w1.w * mk.z + w2.z * mk.w;
    float g2 = w0.z * mk.x + w1.y * mk.y + w2.x * mk.z + w2.w * mk.w;

    #pragma unroll
    for (int off = 8; off >= 1; off >>= 1) {
        p  += __shfl_xor(p,  off);
        a0 += __shfl_xor(a0, off);
        a1 += __shfl_xor(a1, off);
        a2 += __shfl_xor(a2, off);
        g0 += __shfl_xor(g0, off);
        g1 += __shfl_xor(g1, off);
        g2 += __shfl_xor(g2, off);
    }

    if (sub == 0) {
        const float mfm = (s.z != -1)
            ? (BETA * BETA) * (a0 * g0 + a1 * g1 + a2 * g2) : 0.0f;
        out[s.w] = ALPHA * p + mfm;
    }
}

extern "C" void kernel_launch(void* const* d_in, const int* in_sizes, int n_in,
                              void* d_out, int out_size, void* d_ws, size_t ws_size,
                              hipStream_t stream) {
    const float* pF  = (const float*)d_in[0];
    const float* M   = (const float*)d_in[1];
    const int*   ijk = (const int*)d_in[2];
    float* out = (float*)d_out;

    const int B   = in_sizes[2] / 3;     // 500000
    const int N_P = in_sizes[0] / PFW;   // 100000
    const int N_M = in_sizes[1] / R;     // 100000
    const int nb  = (N_P + (1 << BSH) - 1) >> BSH; // 782

    // ws layout: hist[1024] offs[1024] cursor[1024] | pad to 16KB | sorted int4[B] | Mb bf16[N_M*R]
    const size_t sorted_off = 16 * 1024;
    const size_t mb_off     = sorted_off + (size_t)B * sizeof(int4);
    const size_t need_sort  = mb_off;
    const size_t need_full  = mb_off + (size_t)N_M * R * 2;

    int4*  sorted = nullptr;
    uint2* Mb     = nullptr;

    if (nb <= MAXB && ws_size >= need_sort) {
        int* hist   = (int*)d_ws;
        int* offs   = hist + 1024;
        int* cursor = hist + 2048;
        sorted = (int4*)((char*)d_ws + sorted_off);
        const int chunk = (B + SBLK - 1) / SBLK;

        hipMemsetAsync(hist, 0, 1024 * sizeof(int), stream);
        hist_kernel<<<SBLK, 256, 0, stream>>>(ijk, B, chunk, nb, hist);
        scan_kernel<<<1, 1024, 0, stream>>>(hist, offs, cursor, nb);
        scatter_kernel<<<SBLK, 256, 0, stream>>>(ijk, B, chunk, nb, cursor, sorted);
    }
    if (ws_size >= need_full) {
        Mb = (uint2*)((char*)d_ws + mb_off);
        const int n8 = N_M * R / 8;
        convM_kernel<<<(n8 + 255) / 256, 256, 0, stream>>>(M, (uint4*)Mb, n8);
    }

    const int nwg = (B + 15) / 16;   // 16 b's per 256-thread block
    mf_if_kernel<<<nwg, 256, 0, stream>>>(pF, M, Mb, sorted, ijk, out, B, nwg);
}